// Round 1
// baseline (592.687 us; speedup 1.0000x reference)
//
#include <hip/hip_runtime.h>

// pose3d_future loss on MI355X.
// loss = W_PROJ * mean_b( sum_{2,J} (proj(pose)-est)^2 / 42 )
//      + W_BONE * mean_b( sum_bones (bl - |d|^2)^2 / 20 )
// Memory-bound: 252 MB pose + 168 MB est streamed once. Strategy: LDS-staged
// 128-sample tiles with coalesced float4 loads, per-thread compute from LDS,
// hierarchical reduction -> one atomicAdd per block.

namespace {

constexpr float F_    = 525.0f;
constexpr float CX_   = 320.0f;
constexpr float CY_   = 240.0f;
constexpr float WPROJ = 0.33f / 42.0f;   // W_PROJ / (2*J)
constexpr float WBONE = 0.5f  / 20.0f;   // W_BONE / (J-1)
constexpr int   J     = 21;
constexpr int   TILE  = 128;             // samples per block
constexpr int   NT    = 128;             // threads per block (2 waves)

__global__ void pose_loss_kernel(const float* __restrict__ pose,   // [B,3,J]
                                 const float* __restrict__ est,    // [B,2,J]
                                 const float* __restrict__ bl,     // [J-1]
                                 const float* __restrict__ Rm,     // [3,3]
                                 const float* __restrict__ Cd,     // [3,1]
                                 float* __restrict__ out,
                                 int B)
{
    __shared__ float sp[TILE * 63];      // pose tile  (32256 B)
    __shared__ float se[TILE * 42];      // est tile   (21504 B)
    __shared__ float red[NT / 64];

    const int  tid  = threadIdx.x;
    const long tile = blockIdx.x;

    // ---- stage pose tile: TILE*63 floats = 2016 float4, coalesced ----
    {
        const float4* g = (const float4*)pose;
        float4*       s = (float4*)sp;
        const long base  = tile * (TILE * 63 / 4);
        const long total = (long)B * 63 / 4;
        #pragma unroll
        for (int k = 0; k < (TILE * 63 / 4 + NT - 1) / NT; ++k) {
            const int  li = k * NT + tid;
            const long gi = base + li;
            if (li < TILE * 63 / 4 && gi < total) s[li] = g[gi];
        }
    }
    // ---- stage est tile: TILE*42 floats = 1344 float4, coalesced ----
    {
        const float4* g = (const float4*)est;
        float4*       s = (float4*)se;
        const long base  = tile * (TILE * 42 / 4);
        const long total = (long)B * 42 / 4;
        #pragma unroll
        for (int k = 0; k < (TILE * 42 / 4 + NT - 1) / NT; ++k) {
            const int  li = k * NT + tid;
            const long gi = base + li;
            if (li < TILE * 42 / 4 && gi < total) s[li] = g[gi];
        }
    }

    // ---- uniform camera params: M = K @ R^T, M[i][j] = sum_k K[i][k]*R[j][k]
    const float r0 = Rm[0], r1 = Rm[1], r2 = Rm[2];
    const float r3 = Rm[3], r4 = Rm[4], r5 = Rm[5];
    const float r6 = Rm[6], r7 = Rm[7], r8 = Rm[8];
    const float m00 = F_ * r0 + CX_ * r2;
    const float m01 = F_ * r3 + CX_ * r5;
    const float m02 = F_ * r6 + CX_ * r8;
    const float m10 = F_ * r1 + CY_ * r2;
    const float m11 = F_ * r4 + CY_ * r5;
    const float m12 = F_ * r7 + CY_ * r8;
    const float m20 = r2, m21 = r5, m22 = r8;
    const float c0 = Cd[0], c1 = Cd[1], c2 = Cd[2];

    __syncthreads();

    // ---- per-thread: one sample from LDS ----
    float acc = 0.0f;
    const long s_id = tile * TILE + tid;
    if (s_id < B) {
        const float* px = &sp[tid * 63];   // x[0..20], y at +21, z at +42
        const float* eu = &se[tid * 42];   // u-targets, v at +21
        float proj = 0.0f, bone = 0.0f;
        float pvx = 0.f, pvy = 0.f, pvz = 0.f;
        #pragma unroll
        for (int j = 0; j < J; ++j) {
            const float x = px[j]      - c0;
            const float y = px[21 + j] - c1;
            const float z = px[42 + j] - c2;
            const float q0 = m00 * x + m01 * y + m02 * z;
            const float q1 = m10 * x + m11 * y + m12 * z;
            const float q2 = m20 * x + m21 * y + m22 * z;
            const float inv = __builtin_amdgcn_rcpf(q2);   // z ~ 10, safe
            const float du = q0 * inv - eu[j];
            const float dv = q1 * inv - eu[21 + j];
            proj += du * du + dv * dv;
            if (j > 0) {   // kinematic chain bone (j-1, j); C cancels in diff
                const float dx = pvx - x, dy = pvy - y, dz = pvz - z;
                const float sq = dx * dx + dy * dy + dz * dz;
                const float e  = bl[j - 1] - sq;
                bone += e * e;
            }
            pvx = x; pvy = y; pvz = z;
        }
        acc = WPROJ * proj + WBONE * bone;
    }

    // ---- reduction: wave-64 shuffle, then cross-wave via LDS ----
    #pragma unroll
    for (int off = 32; off > 0; off >>= 1)
        acc += __shfl_down(acc, off, 64);
    if ((tid & 63) == 0) red[tid >> 6] = acc;
    __syncthreads();
    if (tid == 0) {
        float b_sum = 0.0f;
        #pragma unroll
        for (int w = 0; w < NT / 64; ++w) b_sum += red[w];
        atomicAdd(out, b_sum * (1.0f / (float)B));
    }
}

} // namespace

extern "C" void kernel_launch(void* const* d_in, const int* in_sizes, int n_in,
                              void* d_out, int out_size, void* d_ws, size_t ws_size,
                              hipStream_t stream) {
    const float* pose = (const float*)d_in[0];
    const float* est  = (const float*)d_in[1];
    const float* bl   = (const float*)d_in[2];
    const float* Rm   = (const float*)d_in[3];
    const float* Cd   = (const float*)d_in[4];
    float* out = (float*)d_out;

    const int B = in_sizes[0] / 63;               // [B,3,21] flat

    hipMemsetAsync(out, 0, sizeof(float), stream);  // d_out is poisoned 0xAA
    const int grid = (B + TILE - 1) / TILE;         // 7813 blocks @ B=1e6
    pose_loss_kernel<<<grid, NT, 0, stream>>>(pose, est, bl, Rm, Cd, out, B);
}

// Round 2
// 506.953 us; speedup vs baseline: 1.1691x; 1.1691x over previous
//
#include <hip/hip_runtime.h>

// pose3d_future loss, round 2: no LDS staging.
// Each thread owns 4 consecutive samples -> its pose bytes (4*63*4 = 1008 B)
// and est bytes (4*42*4 = 672 B) are 16B-aligned blocks, loaded as float4.
// Occupancy no longer LDS-capped (R1: 54 KB/block -> 11% occ, 731 GB/s).
// Boundary-overlap float4 reloads (3 per thread) hit L1, no extra HBM.

namespace {

constexpr float F_    = 525.0f;
constexpr float CX_   = 320.0f;
constexpr float CY_   = 240.0f;
constexpr float WPROJ = 0.33f / 42.0f;   // W_PROJ / (2*J)
constexpr float WBONE = 0.5f  / 20.0f;   // W_BONE / (J-1)
constexpr int   J     = 21;
constexpr int   NT    = 256;             // threads per block (4 waves)
constexpr int   SPT   = 4;               // samples per thread

template <int N>
__device__ __forceinline__ float f4get(const float4 (&A)[N], int idx) {
    // idx is compile-time constant after full unroll -> folds to a register.
    const float4 v = A[idx >> 2];
    const int m = idx & 3;
    return m == 0 ? v.x : (m == 1 ? v.y : (m == 2 ? v.z : v.w));
}

__global__ __launch_bounds__(NT, 3)
void pose_loss_kernel(const float* __restrict__ pose,   // [B,3,J]
                      const float* __restrict__ est,    // [B,2,J]
                      const float* __restrict__ bl,     // [J-1]
                      const float* __restrict__ Rm,     // [3,3]
                      const float* __restrict__ Cd,     // [3,1]
                      float* __restrict__ out,
                      int B)
{
    __shared__ float red[NT / 64];

    const int  tid = threadIdx.x;
    const long t   = (long)blockIdx.x * NT + tid;   // thread id; 4 samples each
    const long s0  = t * SPT;

    // ---- uniform camera params: M = K @ R^T, M[i][j] = sum_k K[i][k]*R[j][k]
    const float r0 = Rm[0], r1 = Rm[1], r2 = Rm[2];
    const float r3 = Rm[3], r4 = Rm[4], r5 = Rm[5];
    const float r6 = Rm[6], r7 = Rm[7], r8 = Rm[8];
    const float m00 = F_ * r0 + CX_ * r2;
    const float m01 = F_ * r3 + CX_ * r5;
    const float m02 = F_ * r6 + CX_ * r8;
    const float m10 = F_ * r1 + CY_ * r2;
    const float m11 = F_ * r4 + CY_ * r5;
    const float m12 = F_ * r7 + CY_ * r8;
    const float m20 = r2, m21 = r5, m22 = r8;
    const float c0 = Cd[0], c1 = Cd[1], c2 = Cd[2];

    // bone targets: 20 scalars, uniform (s_load / L1-resident)
    float blv[J - 1];
    #pragma unroll
    for (int i = 0; i < J - 1; ++i) blv[i] = bl[i];

    float acc = 0.0f;

    if (s0 + SPT - 1 < B) {
        // fast path: 4 aligned samples
        const float4* gp = (const float4*)pose + t * 63;   // 63 f4 = 252 floats
        const float4* ge = (const float4*)est  + t * 42;   // 42 f4 = 168 floats
        #pragma unroll
        for (int k = 0; k < SPT; ++k) {
            const int pbase = (63 * k) >> 2;        // 0,15,31,47
            const int poff  = (63 * k) &  3;        // 0, 3, 2, 1
            const int pcnt  = (k == 0 || k == 3) ? 16 : 17;
            float4 P[17];
            #pragma unroll
            for (int i = 0; i < 17; ++i)
                if (i < pcnt) P[i] = gp[pbase + i];
            const int ebase = (42 * k) >> 2;        // 0,10,21,31
            const int eoff  = (42 * k) &  3;        // 0, 2, 0, 2
            float4 E[11];
            #pragma unroll
            for (int i = 0; i < 11; ++i) E[i] = ge[ebase + i];

            float proj = 0.0f, bone = 0.0f;
            float pvx = 0.f, pvy = 0.f, pvz = 0.f;
            #pragma unroll
            for (int j = 0; j < J; ++j) {
                const float x = f4get(P, poff + j)      - c0;
                const float y = f4get(P, poff + 21 + j) - c1;
                const float z = f4get(P, poff + 42 + j) - c2;
                const float q0 = m00 * x + m01 * y + m02 * z;
                const float q1 = m10 * x + m11 * y + m12 * z;
                const float q2 = m20 * x + m21 * y + m22 * z;
                const float inv = __builtin_amdgcn_rcpf(q2);  // z ~ 10, safe
                const float du = q0 * inv - f4get(E, eoff + j);
                const float dv = q1 * inv - f4get(E, eoff + 21 + j);
                proj += du * du + dv * dv;
                if (j > 0) {
                    const float dx = pvx - x, dy = pvy - y, dz = pvz - z;
                    const float sq = dx * dx + dy * dy + dz * dz;
                    const float e  = blv[j - 1] - sq;
                    bone += e * e;
                }
                pvx = x; pvy = y; pvz = z;
            }
            acc += WPROJ * proj + WBONE * bone;
        }
    } else if (s0 < B) {
        // tail: per-sample scalar loads
        for (long s = s0; s < B && s < s0 + SPT; ++s) {
            const float* px = pose + s * 63;
            const float* eu = est  + s * 42;
            float proj = 0.0f, bone = 0.0f;
            float pvx = 0.f, pvy = 0.f, pvz = 0.f;
            #pragma unroll
            for (int j = 0; j < J; ++j) {
                const float x = px[j]      - c0;
                const float y = px[21 + j] - c1;
                const float z = px[42 + j] - c2;
                const float q0 = m00 * x + m01 * y + m02 * z;
                const float q1 = m10 * x + m11 * y + m12 * z;
                const float q2 = m20 * x + m21 * y + m22 * z;
                const float inv = __builtin_amdgcn_rcpf(q2);
                const float du = q0 * inv - eu[j];
                const float dv = q1 * inv - eu[21 + j];
                proj += du * du + dv * dv;
                if (j > 0) {
                    const float dx = pvx - x, dy = pvy - y, dz = pvz - z;
                    const float sq = dx * dx + dy * dy + dz * dz;
                    const float e  = blv[j - 1] - sq;
                    bone += e * e;
                }
                pvx = x; pvy = y; pvz = z;
            }
            acc += WPROJ * proj + WBONE * bone;
        }
    }

    // ---- reduction: wave-64 shuffle, then cross-wave via LDS ----
    #pragma unroll
    for (int off = 32; off > 0; off >>= 1)
        acc += __shfl_down(acc, off, 64);
    if ((tid & 63) == 0) red[tid >> 6] = acc;
    __syncthreads();
    if (tid == 0) {
        float b_sum = 0.0f;
        #pragma unroll
        for (int w = 0; w < NT / 64; ++w) b_sum += red[w];
        atomicAdd(out, b_sum * (1.0f / (float)B));
    }
}

} // namespace

extern "C" void kernel_launch(void* const* d_in, const int* in_sizes, int n_in,
                              void* d_out, int out_size, void* d_ws, size_t ws_size,
                              hipStream_t stream) {
    const float* pose = (const float*)d_in[0];
    const float* est  = (const float*)d_in[1];
    const float* bl   = (const float*)d_in[2];
    const float* Rm   = (const float*)d_in[3];
    const float* Cd   = (const float*)d_in[4];
    float* out = (float*)d_out;

    const int B = in_sizes[0] / 63;               // [B,3,21] flat

    hipMemsetAsync(out, 0, sizeof(float), stream);  // d_out is poisoned 0xAA
    const long nthreads = ((long)B + SPT - 1) / SPT;
    const int  grid     = (int)((nthreads + NT - 1) / NT);   // 977 @ B=1e6
    pose_loss_kernel<<<grid, NT, 0, stream>>>(pose, est, bl, Rm, Cd, out, B);
}